// Round 3
// baseline (409.634 us; speedup 1.0000x reference)
//
#include <hip/hip_runtime.h>

#define EPS 1e-5f

typedef __bf16 bf16;
typedef bf16 bf16x8 __attribute__((ext_vector_type(8)));
typedef float f32x4 __attribute__((ext_vector_type(4)));
typedef float f32x2 __attribute__((ext_vector_type(2)));

__device__ __forceinline__ void lds_cp16(void* lds, const void* g) {
  __builtin_amdgcn_global_load_lds(
      (const __attribute__((address_space(1))) void*)g,
      (__attribute__((address_space(3))) void*)lds, 16, 0, 0);
}

__device__ __forceinline__ f32x4 mfma_bf16(bf16x8 a, bf16x8 b, f32x4 c) {
  return __builtin_amdgcn_mfma_f32_16x16x32_bf16(a, b, c, 0, 0, 0);
}

// ---------------- zero stats (atomic accumulators) ----------------
__global__ void k_zero(float* p) { p[blockIdx.x * 256 + threadIdx.x] = 0.0f; }

// ---------------- xe = emb[x_id] * clip(x_value, .001, 1) ----------------
__global__ void k_embed(const int* __restrict__ x_id, const float* __restrict__ x_val,
                        const float* __restrict__ emb, float* __restrict__ xe) {
  int g = blockIdx.x * 256 + threadIdx.x;  // (b*64+f)
  int id = x_id[g];
  float v = fminf(fmaxf(x_val[g], 0.001f), 1.0f);
  const float4* er = (const float4*)(emb + (size_t)id * 16);
  float4* xo = (float4*)(xe + (size_t)g * 16);
#pragma unroll
  for (int j = 0; j < 4; ++j) {
    float4 e = er[j];
    e.x *= v; e.y *= v; e.z *= v; e.w *= v;
    xo[j] = e;
  }
}

// ---------------- exp BN stats, coalesced + atomic ----------------
__global__ void k_expstats(const float* __restrict__ xe, float* __restrict__ es,
                           float* __restrict__ eq) {
  int t = threadIdx.x;
  int b0 = blockIdx.x * 16;
  float4 s4 = {0, 0, 0, 0}, q4 = {0, 0, 0, 0};
  for (int i = 0; i < 16; ++i) {
    float4 v = ((const float4*)(xe + (size_t)(b0 + i) * 1024))[t];
    float4 e;
    e.x = __expf(v.x); e.y = __expf(v.y); e.z = __expf(v.z); e.w = __expf(v.w);
    s4.x += e.x; s4.y += e.y; s4.z += e.z; s4.w += e.w;
    q4.x += e.x * e.x; q4.y += e.y * e.y; q4.z += e.z * e.z; q4.w += e.w * e.w;
  }
  float s = (s4.x + s4.y) + (s4.z + s4.w);
  float q = (q4.x + q4.y) + (q4.z + q4.w);
  s += __shfl_xor(s, 1, 64); s += __shfl_xor(s, 2, 64);
  q += __shfl_xor(q, 1, 64); q += __shfl_xor(q, 2, 64);
  if ((t & 3) == 0) {
    int f = t >> 2;
    atomicAdd(es + f, s);
    atomicAdd(eq + f, q);
  }
}

// ---------------- kq (scaled by 0.5) + exp-BN finalize, merged ----------------
__global__ void k_prep(const float* __restrict__ Qw, const float* __restrict__ bil,
                       float* __restrict__ kq, const float* __restrict__ es,
                       const float* __restrict__ eq, const float* __restrict__ g_,
                       const float* __restrict__ b_, float* __restrict__ oa,
                       float* __restrict__ ob) {
  int t = threadIdx.x;  // t = ko
  int k = t >> 5;
  float qv[16];
#pragma unroll
  for (int y = 0; y < 16; ++y) qv[y] = Qw[t * 16 + y];
  const float* bl = bil + k * 256;
#pragma unroll
  for (int x = 0; x < 16; ++x) {
    float s = 0.f;
#pragma unroll
    for (int y = 0; y < 16; ++y) s += bl[x * 16 + y] * qv[y];
    kq[t * 16 + x] = 0.5f * s;  // fold (alpha-1)=0.5 here
  }
  if (t < 64) {
    float mean = es[t] * (1.0f / 65536.0f);
    float var = eq[t] * (1.0f / 65536.0f) - mean * mean;
    float a = g_[t] * rsqrtf(var + EPS);
    oa[t] = a;
    ob[t] = b_[t] - mean * a;
  }
}

// ---------------- per-b: sc, entmax15, aw, arm ----------------
// LDS: phase1 {s_xe[1024]f32, s_sum[16]f32} aliased with phase2 s_aw[256*72]bf16;
// s_X separate. 39168 B total -> 4 blocks/CU.
__global__ __launch_bounds__(256, 4) void k_attn(
    const float* __restrict__ xe_g, const float* __restrict__ kq_g,
    const float* __restrict__ eba, const float* __restrict__ ebb,
    const float* __restrict__ vals, bf16* __restrict__ arm) {
  __shared__ __align__(16) unsigned char smem[39168];
  float* s_xe = (float*)smem;             // phase 1
  float* s_sum = (float*)(smem + 4096);   // phase 1
  bf16* s_aw = (bf16*)smem;               // phase 2 (aliases phase 1)
  bf16* s_X = (bf16*)(smem + 36864);      // 16*72
  const int t = threadIdx.x;
  const int b = blockIdx.x;
  const f32x2 z2 = {0.f, 0.f};

  ((float4*)s_xe)[t] = ((const float4*)(xe_g + (size_t)b * 1024))[t];
  __syncthreads();

  if (t < 16) {
    float s = 0.f;
#pragma unroll
    for (int f = 0; f < 64; ++f) s += s_xe[f * 16 + t];
    s_sum[t] = s;
  }
  {  // x_exp staging: transposed [e][f]
    int f = t >> 2, e0 = (t & 3) * 4;
    float a = eba[f], c = ebb[f];
#pragma unroll
    for (int j = 0; j < 4; ++j) {
      float v = __expf(s_xe[f * 16 + e0 + j]) * a + c;
      s_X[(e0 + j) * 72 + f] = (bf16)v;
    }
  }
  __syncthreads();

  // ---- per-thread: ko = t ----
  f32x2 kq2[8];
  {
    const f32x4* g4 = (const f32x4*)(kq_g + t * 16);
#pragma unroll
    for (int j = 0; j < 4; ++j) {
      f32x4 v = g4[j];
      kq2[2 * j] = __builtin_shufflevector(v, v, 0, 1);
      kq2[2 * j + 1] = __builtin_shufflevector(v, v, 2, 3);
    }
  }
  float gc;
  {
    const f32x2* ss = (const f32x2*)s_sum;
    f32x2 g2 = z2;
#pragma unroll
    for (int i = 0; i < 8; ++i) g2 += ss[i] * kq2[i];
    gc = g2.x + g2.y;
  }

  f32x2 xs2[32];
#pragma unroll
  for (int f = 0; f < 64; ++f) {
    const f32x4* xr = (const f32x4*)(s_xe + f * 16);
    f32x4 A0 = xr[0], A1 = xr[1], A2 = xr[2], A3 = xr[3];
    f32x2 acc = z2;
    acc += __builtin_shufflevector(A0, A0, 0, 1) * kq2[0];
    acc += __builtin_shufflevector(A0, A0, 2, 3) * kq2[1];
    acc += __builtin_shufflevector(A1, A1, 0, 1) * kq2[2];
    acc += __builtin_shufflevector(A1, A1, 2, 3) * kq2[3];
    acc += __builtin_shufflevector(A2, A2, 0, 1) * kq2[4];
    acc += __builtin_shufflevector(A2, A2, 2, 3) * kq2[5];
    acc += __builtin_shufflevector(A3, A3, 0, 1) * kq2[6];
    acc += __builtin_shufflevector(A3, A3, 2, 3) * kq2[7];
    float v = (acc.x + acc.y) + gc;
    if (f & 1) xs2[f >> 1].y = v; else xs2[f >> 1].x = v;
  }
  __syncthreads();  // all s_xe/s_sum reads done; s_aw may now alias

  f32x2 m2 = xs2[0];
#pragma unroll
  for (int i = 1; i < 32; ++i) m2 = __builtin_elementwise_max(m2, xs2[i]);
  float mx = fmaxf(m2.x, m2.y);

  // bisection (f_lo >= 0 always: max element contributes exactly 1 at tau_lo)
  float tau_lo = mx - 1.0f;
  float dm = 0.875f;
#pragma unroll
  for (int it = 0; it < 7; ++it) {
    dm *= 0.5f;
    float tm = tau_lo + dm;
    f32x2 t2 = {tm, tm};
    f32x2 c2 = z2;
#pragma unroll
    for (int i = 0; i < 32; ++i) {
      f32x2 d = xs2[i] - t2;
      d = __builtin_elementwise_max(d, z2);
      c2 += d * d;
    }
    tau_lo = ((c2.x + c2.y) - 1.0f >= 0.f) ? tm : tau_lo;
  }
  // two closed-form support solves from the right bracket end
  float tau = tau_lo + dm;
#pragma unroll
  for (int r = 0; r < 2; ++r) {
    f32x2 t2 = {tau, tau};
    f32x2 S2 = z2, Q2 = z2;
    float cnt = 0.f;
#pragma unroll
    for (int i = 0; i < 32; ++i) {
      f32x2 y = xs2[i] - t2;
      f32x2 m = __builtin_elementwise_max(y, z2);
      S2 += m; Q2 += m * m;
      cnt += (y.x > 0.f ? 1.f : 0.f) + (y.y > 0.f ? 1.f : 0.f);
    }
    float S1 = S2.x + S2.y, Q1 = Q2.x + Q2.y;
    float disc = fmaxf(S1 * S1 - cnt * (Q1 - 1.0f), 0.f);
    tau += (S1 - sqrtf(disc)) / cnt;
  }
  f32x2 Zv = z2;
  {
    f32x2 t2 = {tau, tau};
#pragma unroll
    for (int i = 0; i < 32; ++i) {
      f32x2 d = __builtin_elementwise_max(xs2[i] - t2, z2);
      f32x2 p = d * d;
      xs2[i] = p;
      Zv += p;
    }
  }
  float inv = 1.0f / (Zv.x + Zv.y);

  // aw[ko][f] = (p/Z) * vals[ko][f]  -> bf16 into A-operand layout
  const float4* vg = (const float4*)(vals + t * 64);
#pragma unroll
  for (int f8 = 0; f8 < 64; f8 += 8) {
    float4 v0 = vg[f8 / 4], v1 = vg[f8 / 4 + 1];
    union { bf16 h[8]; uint4 u; } pk;
    pk.h[0] = (bf16)(xs2[f8 / 2].x * inv * v0.x);
    pk.h[1] = (bf16)(xs2[f8 / 2].y * inv * v0.y);
    pk.h[2] = (bf16)(xs2[f8 / 2 + 1].x * inv * v0.z);
    pk.h[3] = (bf16)(xs2[f8 / 2 + 1].y * inv * v0.w);
    pk.h[4] = (bf16)(xs2[f8 / 2 + 2].x * inv * v1.x);
    pk.h[5] = (bf16)(xs2[f8 / 2 + 2].y * inv * v1.y);
    pk.h[6] = (bf16)(xs2[f8 / 2 + 3].x * inv * v1.z);
    pk.h[7] = (bf16)(xs2[f8 / 2 + 3].y * inv * v1.w);
    *(uint4*)(s_aw + t * 72 + f8) = pk.u;
  }
  __syncthreads();

  // arm[ko][e] = sum_f aw[ko][f] * x_exp[f][e]  via MFMA, M=256,N=16,K=64
  const int w = t >> 6, lane = t & 63;
  f32x4 acc[4];
#pragma unroll
  for (int mt = 0; mt < 4; ++mt) acc[mt] = (f32x4){0.f, 0.f, 0.f, 0.f};
#pragma unroll
  for (int ks = 0; ks < 2; ++ks) {
    bf16x8 bfrag = *(const bf16x8*)(s_X + (lane & 15) * 72 + ks * 32 + (lane >> 4) * 8);
#pragma unroll
    for (int mt = 0; mt < 4; ++mt) {
      int row = (w * 4 + mt) * 16 + (lane & 15);
      bf16x8 afrag = *(const bf16x8*)(s_aw + row * 72 + ks * 32 + (lane >> 4) * 8);
      acc[mt] = mfma_bf16(afrag, bfrag, acc[mt]);
    }
  }
  bf16* armb = arm + (size_t)b * 4096;
#pragma unroll
  for (int mt = 0; mt < 4; ++mt) {
    int ko0 = (w * 4 + mt) * 16 + (lane >> 4) * 4;
#pragma unroll
    for (int r = 0; r < 4; ++r)
      armb[(ko0 + r) * 16 + (lane & 15)] = (bf16)acc[mt][r];
  }
}

// ---------------- arm BN stats, coalesced + atomic ----------------
__global__ void k_armstats(const bf16* __restrict__ arm, float* __restrict__ as_,
                           float* __restrict__ aq) {
  int t = threadIdx.x;
  int b0 = blockIdx.x * 8;
  float s = 0.f, q = 0.f;
  for (int i = 0; i < 8; ++i) {
    const bf16* p = arm + (size_t)(b0 + i) * 4096 + t * 16;
    bf16x8 v0 = *(const bf16x8*)p;
    bf16x8 v1 = *(const bf16x8*)(p + 8);
#pragma unroll
    for (int j = 0; j < 8; ++j) {
      float a = (float)v0[j], c = (float)v1[j];
      s += a + c; q += a * a + c * c;
    }
  }
  atomicAdd(as_ + t, s);
  atomicAdd(aq + t, q);
}

__global__ void k_armfin(const float* __restrict__ as_, const float* __restrict__ aq,
                         const float* __restrict__ g_, float* __restrict__ oa) {
  int ko = threadIdx.x;  // 256; BN shift cancels in BN1 -> only scale needed
  float mean = as_[ko] * (1.0f / 65536.0f);
  float var = aq[ko] * (1.0f / 65536.0f) - mean * mean;
  oa[ko] = g_[ko] * rsqrtf(var + EPS);
}

// ---------------- w1 convert with fused arm-BN column scale ----------------
__global__ void k_cvtw1s(const float* __restrict__ s, const float* __restrict__ a,
                         bf16* __restrict__ d, int n4) {
  int stride = gridDim.x * 256;
  for (int i = blockIdx.x * 256 + threadIdx.x; i < n4; i += stride) {
    float4 v = ((const float4*)s)[i];
    float av = a[(i >> 2) & 255];
    union { bf16 h[4]; uint2 u; } p;
    p.h[0] = (bf16)(v.x * av); p.h[1] = (bf16)(v.y * av);
    p.h[2] = (bf16)(v.z * av); p.h[3] = (bf16)(v.w * av);
    *(uint2*)(d + (size_t)i * 4) = p.u;
  }
}

// ---------------- fp32 -> bf16 convert ----------------
__global__ void k_cvt(const float* __restrict__ s, bf16* __restrict__ d, int n4) {
  int stride = gridDim.x * 256;
  for (int i = blockIdx.x * 256 + threadIdx.x; i < n4; i += stride) {
    float4 v = ((const float4*)s)[i];
    union { bf16 h[4]; uint2 u; } p;
    p.h[0] = (bf16)v.x; p.h[1] = (bf16)v.y; p.h[2] = (bf16)v.z; p.h[3] = (bf16)v.w;
    *(uint2*)(d + (size_t)i * 4) = p.u;
  }
}

// ------------- bf16 NT GEMM 128x128xBK32, split-K -> separate partials -------------
__global__ __launch_bounds__(256, 2) void gemm_sk(
    const bf16* __restrict__ A, const bf16* __restrict__ Bw,
    float* __restrict__ P0, float* __restrict__ P1, int Ktot, int Kd) {
  __shared__ __align__(16) bf16 sA[128 * 32];
  __shared__ __align__(16) bf16 sB[128 * 32];
  const int t = threadIdx.x;
  const int w = t >> 6, lane = t & 63;
  const int m0 = blockIdx.x * 128, n0 = blockIdx.y * 128;
  const int k0 = blockIdx.z * Kd;
  float* P = blockIdx.z ? P1 : P0;
  const int wr = (w >> 1) * 64, wc = (w & 1) * 64;

  f32x4 acc[4][4];
#pragma unroll
  for (int i = 0; i < 4; ++i)
#pragma unroll
    for (int j = 0; j < 4; ++j) acc[i][j] = (f32x4){0.f, 0.f, 0.f, 0.f};

  for (int kt = 0; kt < Kd; kt += 32) {
#pragma unroll
    for (int c = 0; c < 2; ++c) {
      int idx = c * 256 + t;
      int row = idx >> 2, ch = idx & 3;
      int sch = ch ^ ((row >> 1) & 3);  // XOR swizzle breaks ds_read bank conflicts
      lds_cp16(sA + idx * 8, A + (size_t)(m0 + row) * Ktot + k0 + kt + sch * 8);
      lds_cp16(sB + idx * 8, Bw + (size_t)(n0 + row) * Ktot + k0 + kt + sch * 8);
    }
    __syncthreads();
    bf16x8 af[4], bfr[4];
#pragma unroll
    for (int mt = 0; mt < 4; ++mt) {
      int row = wr + mt * 16 + (lane & 15);
      int ch = (lane >> 4) ^ ((row >> 1) & 3);
      af[mt] = *(const bf16x8*)(sA + row * 32 + ch * 8);
    }
#pragma unroll
    for (int nt = 0; nt < 4; ++nt) {
      int row = wc + nt * 16 + (lane & 15);
      int ch = (lane >> 4) ^ ((row >> 1) & 3);
      bfr[nt] = *(const bf16x8*)(sB + row * 32 + ch * 8);
    }
#pragma unroll
    for (int mt = 0; mt < 4; ++mt)
#pragma unroll
      for (int nt = 0; nt < 4; ++nt)
        acc[mt][nt] = mfma_bf16(af[mt], bfr[nt], acc[mt][nt]);
    __syncthreads();
  }

#pragma unroll
  for (int nt = 0; nt < 4; ++nt) {
    int ncol = n0 + wc + nt * 16 + (lane & 15);
#pragma unroll
    for (int mt = 0; mt < 4; ++mt) {
      int mr = m0 + wr + mt * 16 + (lane >> 4) * 4;
#pragma unroll
      for (int r = 0; r < 4; ++r)
        P[(size_t)(mr + r) * 1024 + ncol] = acc[mt][nt][r];
    }
  }
}

// ---------------- column stats of (P0+P1), atomic ----------------
__global__ void k_colstats(const float* __restrict__ P0, const float* __restrict__ P1,
                           float* __restrict__ cs, float* __restrict__ cq) {
  int t = threadIdx.x;
  int r0 = blockIdx.x * 16;
  float4 s4 = {0, 0, 0, 0}, q4 = {0, 0, 0, 0};
  for (int i = 0; i < 16; ++i) {
    float4 a = ((const float4*)(P0 + (size_t)(r0 + i) * 1024))[t];
    float4 b = ((const float4*)(P1 + (size_t)(r0 + i) * 1024))[t];
    float4 v;
    v.x = a.x + b.x; v.y = a.y + b.y; v.z = a.z + b.z; v.w = a.w + b.w;
    s4.x += v.x; s4.y += v.y; s4.z += v.z; s4.w += v.w;
    q4.x += v.x * v.x; q4.y += v.y * v.y; q4.z += v.z * v.z; q4.w += v.w * v.w;
  }
  int c0 = t * 4;
  atomicAdd(cs + c0 + 0, s4.x); atomicAdd(cs + c0 + 1, s4.y);
  atomicAdd(cs + c0 + 2, s4.z); atomicAdd(cs + c0 + 3, s4.w);
  atomicAdd(cq + c0 + 0, q4.x); atomicAdd(cq + c0 + 1, q4.y);
  atomicAdd(cq + c0 + 2, q4.z); atomicAdd(cq + c0 + 3, q4.w);
}

// ---------------- finalize per-column BN coefficients ----------------
__global__ void k_colfin(const float* __restrict__ s, const float* __restrict__ q,
                         const float* __restrict__ g_, const float* __restrict__ bt,
                         float* __restrict__ a, float* __restrict__ c) {
  int h = blockIdx.x * 256 + threadIdx.x;  // < 1024
  float mean = s[h] * (1.0f / 4096.0f);
  float var = q[h] * (1.0f / 4096.0f) - mean * mean;
  float av = g_[h] * rsqrtf(var + EPS);
  a[h] = av;
  c[h] = bt[h] - mean * av;
}

// ---------------- h1 = relu(bn(P0+P1)) -> bf16 ----------------
__global__ void k_h1bf(const float* __restrict__ P0, const float* __restrict__ P1,
                       const float* __restrict__ a, const float* __restrict__ c,
                       bf16* __restrict__ H1) {
  int i4 = blockIdx.x * 256 + threadIdx.x;  // over 1048576
  int col0 = (i4 * 4) & 1023;
  float4 u = ((const float4*)P0)[i4];
  float4 v = ((const float4*)P1)[i4];
  float4 av = *(const float4*)(a + col0);
  float4 cv = *(const float4*)(c + col0);
  union { bf16 h[4]; uint2 u; } pk;
  pk.h[0] = (bf16)fmaxf((u.x + v.x) * av.x + cv.x, 0.f);
  pk.h[1] = (bf16)fmaxf((u.y + v.y) * av.y + cv.y, 0.f);
  pk.h[2] = (bf16)fmaxf((u.z + v.z) * av.z + cv.z, 0.f);
  pk.h[3] = (bf16)fmaxf((u.w + v.w) * av.w + cv.w, 0.f);
  *(uint2*)(H1 + (size_t)i4 * 4) = pk.u;
}

// ---------------- y[b] = sum_h relu(bn(P0+P1)) * wout + bout ----------------
__global__ __launch_bounds__(256) void k_out(const float* __restrict__ P0,
                                             const float* __restrict__ P1,
                                             const float* __restrict__ a,
                                             const float* __restrict__ c,
                                             const float* __restrict__ wout,
                                             const float* __restrict__ bout,
                                             float* __restrict__ y) {
  int t = threadIdx.x;
  int w = t >> 6, lane = t & 63;
  int row = blockIdx.x * 4 + w;
  const float* r0 = P0 + (size_t)row * 1024;
  const float* r1 = P1 + (size_t)row * 1024;
  float s = 0.f;
#pragma unroll
  for (int j = 0; j < 16; ++j) {
    int col = j * 64 + lane;
    float v = fmaxf((r0[col] + r1[col]) * a[col] + c[col], 0.f);
    s += v * wout[col];
  }
#pragma unroll
  for (int off = 32; off > 0; off >>= 1) s += __shfl_xor(s, off, 64);
  if (lane == 0) y[row] = s + bout[0];
}

extern "C" void kernel_launch(void* const* d_in, const int* in_sizes, int n_in,
                              void* d_out, int out_size, void* d_ws, size_t ws_size,
                              hipStream_t stream) {
  (void)in_sizes; (void)n_in; (void)out_size; (void)ws_size;
  const int* x_id = (const int*)d_in[0];
  const float* x_value = (const float*)d_in[1];
  const float* emb = (const float*)d_in[2];
  const float* emb_g = (const float*)d_in[3];
  const float* embb = (const float*)d_in[4];
  const float* Qw = (const float*)d_in[5];
  const float* bil = (const float*)d_in[6];
  const float* vals = (const float*)d_in[7];
  const float* arm_g = (const float*)d_in[8];
  const float* w1 = (const float*)d_in[10];
  const float* g1 = (const float*)d_in[12];
  const float* bt1 = (const float*)d_in[13];
  const float* w2 = (const float*)d_in[14];
  const float* g2 = (const float*)d_in[16];
  const float* bt2 = (const float*)d_in[17];
  const float* wout = (const float*)d_in[18];
  const float* bout = (const float*)d_in[19];
  // b1, b2, arm_b unused: per-column shifts cancel exactly in train-mode BN.

  char* w = (char*)d_ws;
  float* ws_A = (float*)w;                  // 16 MB: xe -> P0 (gemm1) -> P0' (gemm2)
  bf16* ws_arm = (bf16*)(w + 16777216);     // 32 MB: arm bf16 (dead after gemm1)
  float* ws_D = (float*)(w + 50331648);     // 16 MB: P1 (gemm1) -> P1' (gemm2)
  bf16* ws_w1b = (bf16*)(w + 67108864);     // 8 MB: w1*scale bf16; H1 after gemm1
  bf16* ws_H1 = ws_w1b;
  bf16* ws_w2b = (bf16*)(w + 75497472);     // 2 MB
  float* ws_kq = (float*)(w + 77594624);    // 16 KB
  float* st = (float*)(w + 77611008);       // stats region
  // zeroed block [0,5120):
  float* es = st;            // 64
  float* eq = es + 64;       // 64
  float* as_ = eq + 64;      // 256
  float* aq = as_ + 256;     // 256
  float* s1 = aq + 256;      // 1024
  float* q1 = s1 + 1024;
  float* s2 = q1 + 1024;
  float* q2 = s2 + 1024;     // ends 4736
  // non-zeroed:
  float* eb_a = st + 5120;   // 64
  float* eb_b = eb_a + 64;
  float* arm_a = eb_b + 64;  // 256
  float* a1c = arm_a + 256;  // 1024
  float* c1c = a1c + 1024;
  float* a2c = c1c + 1024;
  float* c2c = a2c + 1024;

  k_zero<<<20, 256, 0, stream>>>(st);
  k_embed<<<1024, 256, 0, stream>>>(x_id, x_value, emb, ws_A);
  k_expstats<<<256, 256, 0, stream>>>(ws_A, es, eq);
  k_prep<<<1, 256, 0, stream>>>(Qw, bil, ws_kq, es, eq, emb_g, embb, eb_a, eb_b);
  k_attn<<<4096, 256, 0, stream>>>(ws_A, ws_kq, eb_a, eb_b, vals, ws_arm);
  k_armstats<<<512, 256, 0, stream>>>(ws_arm, as_, aq);
  k_armfin<<<1, 256, 0, stream>>>(as_, aq, arm_g, arm_a);
  k_cvtw1s<<<1024, 256, 0, stream>>>(w1, arm_a, ws_w1b, 1048576);
  k_cvt<<<256, 256, 0, stream>>>(w2, ws_w2b, 262144);
  gemm_sk<<<dim3(32, 8, 2), 256, 0, stream>>>(ws_arm, ws_w1b, ws_A, ws_D, 4096, 2048);
  k_colstats<<<256, 256, 0, stream>>>(ws_A, ws_D, s1, q1);
  k_colfin<<<4, 256, 0, stream>>>(s1, q1, g1, bt1, a1c, c1c);
  k_h1bf<<<4096, 256, 0, stream>>>(ws_A, ws_D, a1c, c1c, ws_H1);
  gemm_sk<<<dim3(32, 8, 2), 256, 0, stream>>>(ws_H1, ws_w2b, ws_A, ws_D, 1024, 512);
  k_colstats<<<256, 256, 0, stream>>>(ws_A, ws_D, s2, q2);
  k_colfin<<<4, 256, 0, stream>>>(s2, q2, g2, bt2, a2c, c2c);
  k_out<<<1024, 256, 0, stream>>>(ws_A, ws_D, a2c, c2c, wout, bout, (float*)d_out);
}

// Round 4
// 341.768 us; speedup vs baseline: 1.1986x; 1.1986x over previous
//
#include <hip/hip_runtime.h>

#define EPS 1e-5f

typedef __bf16 bf16;
typedef bf16 bf16x8 __attribute__((ext_vector_type(8)));
typedef float f32x4 __attribute__((ext_vector_type(4)));
typedef float f32x2 __attribute__((ext_vector_type(2)));

__device__ __forceinline__ void lds_cp16(void* lds, const void* g) {
  __builtin_amdgcn_global_load_lds(
      (const __attribute__((address_space(1))) void*)g,
      (__attribute__((address_space(3))) void*)lds, 16, 0, 0);
}

__device__ __forceinline__ f32x4 mfma_bf16(bf16x8 a, bf16x8 b, f32x4 c) {
  return __builtin_amdgcn_mfma_f32_16x16x32_bf16(a, b, c, 0, 0, 0);
}

// ------- embed: xe = emb[x_id]*clip(v) ; fused exp-BN per-block partial stats -------
// grid 256 x 256 thr, 4 items/thread; f = (b*64+f)&63 = t&63 (constant per thread)
__global__ void k_embed(const int* __restrict__ x_id, const float* __restrict__ x_val,
                        const float* __restrict__ emb, float* __restrict__ xe,
                        float* __restrict__ es_p, float* __restrict__ eq_p) {
  int t = threadIdx.x, bid = blockIdx.x;
  float s = 0.f, q = 0.f;
#pragma unroll
  for (int it = 0; it < 4; ++it) {
    int g = it * 65536 + bid * 256 + t;
    int id = x_id[g];
    float v = fminf(fmaxf(x_val[g], 0.001f), 1.0f);
    const float4* er = (const float4*)(emb + (size_t)id * 16);
    float4* xo = (float4*)(xe + (size_t)g * 16);
#pragma unroll
    for (int j = 0; j < 4; ++j) {
      float4 e = er[j];
      e.x *= v; e.y *= v; e.z *= v; e.w *= v;
      xo[j] = e;
      float a0 = __expf(e.x), a1 = __expf(e.y), a2 = __expf(e.z), a3 = __expf(e.w);
      s += (a0 + a1) + (a2 + a3);
      q += (a0 * a0 + a1 * a1) + (a2 * a2 + a3 * a3);
    }
  }
  __shared__ float rs[256], rq[256];
  rs[t] = s; rq[t] = q;
  __syncthreads();
  if (t < 64) {
    float S = rs[t] + rs[t + 64] + rs[t + 128] + rs[t + 192];
    float Q = rq[t] + rq[t + 64] + rq[t + 128] + rq[t + 192];
    es_p[bid * 64 + t] = S;
    eq_p[bid * 64 + t] = Q;
  }
}

// ------- kq (x0.5) + exp-BN finalize (reduce 256 partials) -------
__global__ void k_prep(const float* __restrict__ Qw, const float* __restrict__ bil,
                       float* __restrict__ kq, const float* __restrict__ es_p,
                       const float* __restrict__ eq_p, const float* __restrict__ g_,
                       const float* __restrict__ b_, float* __restrict__ oa,
                       float* __restrict__ ob) {
  int t = threadIdx.x;  // t = ko
  int k = t >> 5;
  float qv[16];
#pragma unroll
  for (int y = 0; y < 16; ++y) qv[y] = Qw[t * 16 + y];
  const float* bl = bil + k * 256;
#pragma unroll
  for (int x = 0; x < 16; ++x) {
    float s = 0.f;
#pragma unroll
    for (int y = 0; y < 16; ++y) s += bl[x * 16 + y] * qv[y];
    kq[t * 16 + x] = 0.5f * s;  // fold (alpha-1)=0.5
  }
  if (t < 64) {
    float S = 0.f, Q = 0.f;
    for (int i = 0; i < 256; ++i) { S += es_p[i * 64 + t]; Q += eq_p[i * 64 + t]; }
    float mean = S * (1.0f / 65536.0f);
    float var = Q * (1.0f / 65536.0f) - mean * mean;
    float a = g_[t] * rsqrtf(var + EPS);
    oa[t] = a;
    ob[t] = b_[t] - mean * a;
  }
}

// ---------------- per-b: sc, entmax15, aw, arm ----------------
__global__ __launch_bounds__(256, 4) void k_attn(
    const float* __restrict__ xe_g, const float* __restrict__ kq_g,
    const float* __restrict__ eba, const float* __restrict__ ebb,
    const float* __restrict__ vals, bf16* __restrict__ arm) {
  __shared__ __align__(16) unsigned char smem[39168];
  float* s_xe = (float*)smem;             // phase 1
  float* s_sum = (float*)(smem + 4096);   // phase 1
  bf16* s_aw = (bf16*)smem;               // phase 2 (aliases phase 1)
  float* s_out = (float*)smem;            // phase 3 [16][257] (aliases again)
  bf16* s_X = (bf16*)(smem + 36864);      // 16*72
  const int t = threadIdx.x;
  const int b = blockIdx.x;
  const f32x2 z2 = {0.f, 0.f};

  ((float4*)s_xe)[t] = ((const float4*)(xe_g + (size_t)b * 1024))[t];
  __syncthreads();

  if (t < 16) {
    float s = 0.f;
#pragma unroll
    for (int f = 0; f < 64; ++f) s += s_xe[f * 16 + t];
    s_sum[t] = s;
  }
  {  // x_exp staging: transposed [e][f]
    int f = t >> 2, e0 = (t & 3) * 4;
    float a = eba[f], c = ebb[f];
#pragma unroll
    for (int j = 0; j < 4; ++j) {
      float v = __expf(s_xe[f * 16 + e0 + j]) * a + c;
      s_X[(e0 + j) * 72 + f] = (bf16)v;
    }
  }
  __syncthreads();

  // ---- per-thread: ko = t ----
  f32x2 kq2[8];
  {
    const f32x4* g4 = (const f32x4*)(kq_g + t * 16);
#pragma unroll
    for (int j = 0; j < 4; ++j) {
      f32x4 v = g4[j];
      kq2[2 * j] = __builtin_shufflevector(v, v, 0, 1);
      kq2[2 * j + 1] = __builtin_shufflevector(v, v, 2, 3);
    }
  }
  float gc;
  {
    const f32x2* ss = (const f32x2*)s_sum;
    f32x2 g2 = z2;
#pragma unroll
    for (int i = 0; i < 8; ++i) g2 += ss[i] * kq2[i];
    gc = g2.x + g2.y;
  }

  f32x2 xs2[32];
#pragma unroll
  for (int f = 0; f < 64; ++f) {
    const f32x4* xr = (const f32x4*)(s_xe + f * 16);
    f32x4 A0 = xr[0], A1 = xr[1], A2 = xr[2], A3 = xr[3];
    f32x2 acc = z2;
    acc += __builtin_shufflevector(A0, A0, 0, 1) * kq2[0];
    acc += __builtin_shufflevector(A0, A0, 2, 3) * kq2[1];
    acc += __builtin_shufflevector(A1, A1, 0, 1) * kq2[2];
    acc += __builtin_shufflevector(A1, A1, 2, 3) * kq2[3];
    acc += __builtin_shufflevector(A2, A2, 0, 1) * kq2[4];
    acc += __builtin_shufflevector(A2, A2, 2, 3) * kq2[5];
    acc += __builtin_shufflevector(A3, A3, 0, 1) * kq2[6];
    acc += __builtin_shufflevector(A3, A3, 2, 3) * kq2[7];
    float v = (acc.x + acc.y) + gc;
    if (f & 1) xs2[f >> 1].y = v; else xs2[f >> 1].x = v;
  }
  __syncthreads();  // s_xe/s_sum dead; s_aw may alias

  f32x2 m2 = xs2[0];
#pragma unroll
  for (int i = 1; i < 32; ++i) m2 = __builtin_elementwise_max(m2, xs2[i]);
  float mx = fmaxf(m2.x, m2.y);

  float tau_lo = mx - 1.0f;  // f_lo >= 0 always
  float dm = 0.875f;
#pragma unroll
  for (int it = 0; it < 7; ++it) {
    dm *= 0.5f;
    float tm = tau_lo + dm;
    f32x2 t2 = {tm, tm};
    f32x2 c2 = z2;
#pragma unroll
    for (int i = 0; i < 32; ++i) {
      f32x2 d = xs2[i] - t2;
      d = __builtin_elementwise_max(d, z2);
      c2 += d * d;
    }
    tau_lo = ((c2.x + c2.y) - 1.0f >= 0.f) ? tm : tau_lo;
  }
  float tau = tau_lo + dm;
#pragma unroll
  for (int r = 0; r < 2; ++r) {
    f32x2 t2 = {tau, tau};
    f32x2 S2 = z2, Q2 = z2;
    float cnt = 0.f;
#pragma unroll
    for (int i = 0; i < 32; ++i) {
      f32x2 y = xs2[i] - t2;
      f32x2 m = __builtin_elementwise_max(y, z2);
      S2 += m; Q2 += m * m;
      cnt += (y.x > 0.f ? 1.f : 0.f) + (y.y > 0.f ? 1.f : 0.f);
    }
    float S1 = S2.x + S2.y, Q1 = Q2.x + Q2.y;
    float disc = fmaxf(S1 * S1 - cnt * (Q1 - 1.0f), 0.f);
    tau += (S1 - sqrtf(disc)) / cnt;
  }
  f32x2 Zv = z2;
  {
    f32x2 t2 = {tau, tau};
#pragma unroll
    for (int i = 0; i < 32; ++i) {
      f32x2 d = __builtin_elementwise_max(xs2[i] - t2, z2);
      f32x2 p = d * d;
      xs2[i] = p;
      Zv += p;
    }
  }
  float inv = 1.0f / (Zv.x + Zv.y);

  // aw[ko][f] -> bf16 A-operand layout
  const float4* vg = (const float4*)(vals + t * 64);
#pragma unroll
  for (int f8 = 0; f8 < 64; f8 += 8) {
    float4 v0 = vg[f8 / 4], v1 = vg[f8 / 4 + 1];
    union { bf16 h[8]; uint4 u; } pk;
    pk.h[0] = (bf16)(xs2[f8 / 2].x * inv * v0.x);
    pk.h[1] = (bf16)(xs2[f8 / 2].y * inv * v0.y);
    pk.h[2] = (bf16)(xs2[f8 / 2 + 1].x * inv * v0.z);
    pk.h[3] = (bf16)(xs2[f8 / 2 + 1].y * inv * v0.w);
    pk.h[4] = (bf16)(xs2[f8 / 2 + 2].x * inv * v1.x);
    pk.h[5] = (bf16)(xs2[f8 / 2 + 2].y * inv * v1.y);
    pk.h[6] = (bf16)(xs2[f8 / 2 + 3].x * inv * v1.z);
    pk.h[7] = (bf16)(xs2[f8 / 2 + 3].y * inv * v1.w);
    *(uint4*)(s_aw + t * 72 + f8) = pk.u;
  }
  __syncthreads();

  // arm[ko][e] = sum_f aw[ko][f] * x_exp[f][e]  (MFMA, M=256,N=16,K=64)
  const int w = t >> 6, lane = t & 63;
  f32x4 acc[4];
#pragma unroll
  for (int mt = 0; mt < 4; ++mt) acc[mt] = (f32x4){0.f, 0.f, 0.f, 0.f};
#pragma unroll
  for (int ks = 0; ks < 2; ++ks) {
    bf16x8 bfrag = *(const bf16x8*)(s_X + (lane & 15) * 72 + ks * 32 + (lane >> 4) * 8);
#pragma unroll
    for (int mt = 0; mt < 4; ++mt) {
      int row = (w * 4 + mt) * 16 + (lane & 15);
      bf16x8 afrag = *(const bf16x8*)(s_aw + row * 72 + ks * 32 + (lane >> 4) * 8);
      acc[mt] = mfma_bf16(afrag, bfrag, acc[mt]);
    }
  }
  __syncthreads();  // MFMA inputs consumed; reuse smem for store bounce
  // stage C-layout accs into LDS [e][ko] (stride 257: conflict-free both ways)
#pragma unroll
  for (int mt = 0; mt < 4; ++mt) {
    int ko0 = (w * 4 + mt) * 16 + (lane >> 4) * 4;
#pragma unroll
    for (int r = 0; r < 4; ++r)
      s_out[(lane & 15) * 257 + ko0 + r] = acc[mt][r];
  }
  __syncthreads();
  // coalesced write: thread t packs row ko=t (16 elems) as 2x uint4
  union { bf16 h[16]; uint4 u[2]; } pk;
#pragma unroll
  for (int e = 0; e < 16; ++e) pk.h[e] = (bf16)s_out[e * 257 + t];
  uint4* dst = (uint4*)(arm + (size_t)b * 4096 + t * 16);
  dst[0] = pk.u[0];
  dst[1] = pk.u[1];
}

// ------- arm BN per-block partial stats (64 blocks x 64 rows, coalesced) -------
__global__ void k_armstats(const bf16* __restrict__ arm, float* __restrict__ as_p,
                           float* __restrict__ aq_p) {
  int t = threadIdx.x;
  int b0 = blockIdx.x * 64;
  float s = 0.f, q = 0.f;
  for (int i = 0; i < 64; ++i) {
    const bf16* p = arm + (size_t)(b0 + i) * 4096 + t * 16;
    bf16x8 v0 = *(const bf16x8*)p;
    bf16x8 v1 = *(const bf16x8*)(p + 8);
#pragma unroll
    for (int j = 0; j < 8; ++j) {
      float a = (float)v0[j], c = (float)v1[j];
      s += a + c; q += a * a + c * c;
    }
  }
  as_p[blockIdx.x * 256 + t] = s;
  aq_p[blockIdx.x * 256 + t] = q;
}

// ------- weight convert: blocks [0,256) w1 * arm-scale (inline reduce); [256,320) w2 -------
__global__ void k_cvtw(const float* __restrict__ w1, const float* __restrict__ w2,
                       const float* __restrict__ as_p, const float* __restrict__ aq_p,
                       const float* __restrict__ arm_g, bf16* __restrict__ d1,
                       bf16* __restrict__ d2) {
  int t = threadIdx.x, bid = blockIdx.x;
  if (bid < 256) {
    __shared__ float scale[256];
    float s = 0.f, q = 0.f;
    for (int i = 0; i < 64; ++i) { s += as_p[i * 256 + t]; q += aq_p[i * 256 + t]; }
    float mean = s * (1.0f / 65536.0f);
    float var = q * (1.0f / 65536.0f) - mean * mean;
    scale[t] = arm_g[t] * rsqrtf(var + EPS);  // BN shift cancels in BN1
    __syncthreads();
#pragma unroll
    for (int it = 0; it < 16; ++it) {
      int i = it * 65536 + bid * 256 + t;
      float4 v = ((const float4*)w1)[i];
      float av = scale[(i >> 2) & 255];
      union { bf16 h[4]; uint2 u; } p;
      p.h[0] = (bf16)(v.x * av); p.h[1] = (bf16)(v.y * av);
      p.h[2] = (bf16)(v.z * av); p.h[3] = (bf16)(v.w * av);
      *(uint2*)(d1 + (size_t)i * 4) = p.u;
    }
  } else {
#pragma unroll
    for (int it = 0; it < 16; ++it) {
      int i = it * 16384 + (bid - 256) * 256 + t;
      float4 v = ((const float4*)w2)[i];
      union { bf16 h[4]; uint2 u; } p;
      p.h[0] = (bf16)v.x; p.h[1] = (bf16)v.y; p.h[2] = (bf16)v.z; p.h[3] = (bf16)v.w;
      *(uint2*)(d2 + (size_t)i * 4) = p.u;
    }
  }
}

// ------- bf16 NT GEMM 128x64xBK32 full-K + per-mblock column partial stats -------
__global__ __launch_bounds__(256, 2) void gemm_bt(
    const bf16* __restrict__ A, const bf16* __restrict__ Bw, float* __restrict__ C,
    float* __restrict__ sp, float* __restrict__ sq, int Kd) {
  __shared__ __align__(16) bf16 sA[128 * 32];
  __shared__ __align__(16) bf16 sB[64 * 32];
  __shared__ float sredS[4][64], sredQ[4][64];
  const int t = threadIdx.x;
  const int w = t >> 6, lane = t & 63;
  const int m0 = blockIdx.x * 128, n0 = blockIdx.y * 64;

  f32x4 acc[2][4];
#pragma unroll
  for (int i = 0; i < 2; ++i)
#pragma unroll
    for (int j = 0; j < 4; ++j) acc[i][j] = (f32x4){0.f, 0.f, 0.f, 0.f};

  for (int kt = 0; kt < Kd; kt += 32) {
#pragma unroll
    for (int c = 0; c < 2; ++c) {
      int idx = c * 256 + t;
      int row = idx >> 2, ch = idx & 3;
      int sch = ch ^ ((row >> 1) & 3);  // XOR swizzle
      lds_cp16(sA + idx * 8, A + (size_t)(m0 + row) * Kd + kt + sch * 8);
    }
    {
      int row = t >> 2, ch = t & 3;
      int sch = ch ^ ((row >> 1) & 3);
      lds_cp16(sB + t * 8, Bw + (size_t)(n0 + row) * Kd + kt + sch * 8);
    }
    __syncthreads();
    bf16x8 af[2], bfr[4];
#pragma unroll
    for (int mt = 0; mt < 2; ++mt) {
      int row = w * 32 + mt * 16 + (lane & 15);
      int ch = (lane >> 4) ^ ((row >> 1) & 3);
      af[mt] = *(const bf16x8*)(sA + row * 32 + ch * 8);
    }
#pragma unroll
    for (int nt = 0; nt < 4; ++nt) {
      int row = nt * 16 + (lane & 15);
      int ch = (lane >> 4) ^ ((row >> 1) & 3);
      bfr[nt] = *(const bf16x8*)(sB + row * 32 + ch * 8);
    }
#pragma unroll
    for (int mt = 0; mt < 2; ++mt)
#pragma unroll
      for (int nt = 0; nt < 4; ++nt)
        acc[mt][nt] = mfma_bf16(af[mt], bfr[nt], acc[mt][nt]);
    __syncthreads();
  }

#pragma unroll
  for (int nt = 0; nt < 4; ++nt) {
    int ncol = n0 + nt * 16 + (lane & 15);
    float s = 0.f, q = 0.f;
#pragma unroll
    for (int mt = 0; mt < 2; ++mt) {
      int mr = m0 + w * 32 + mt * 16 + (lane >> 4) * 4;
#pragma unroll
      for (int r = 0; r < 4; ++r) {
        float v = acc[mt][nt][r];
        C[(size_t)(mr + r) * 1024 + ncol] = v;
        s += v; q += v * v;
      }
    }
    s += __shfl_xor(s, 16, 64); s += __shfl_xor(s, 32, 64);
    q += __shfl_xor(q, 16, 64); q += __shfl_xor(q, 32, 64);
    if (lane < 16) { sredS[w][nt * 16 + lane] = s; sredQ[w][nt * 16 + lane] = q; }
  }
  __syncthreads();
  if (t < 64) {
    float S = sredS[0][t] + sredS[1][t] + sredS[2][t] + sredS[3][t];
    float Q = sredQ[0][t] + sredQ[1][t] + sredQ[2][t] + sredQ[3][t];
    sp[blockIdx.x * 1024 + n0 + t] = S;
    sq[blockIdx.x * 1024 + n0 + t] = Q;
  }
}

// ------- finalize per-column BN coefficients from 32 m-block partials -------
__global__ void k_colfin(const float* __restrict__ sp, const float* __restrict__ sq,
                         const float* __restrict__ g_, const float* __restrict__ bt,
                         float* __restrict__ a, float* __restrict__ c) {
  int h = blockIdx.x * 256 + threadIdx.x;  // < 1024
  float S = 0.f, Q = 0.f;
  for (int i = 0; i < 32; ++i) { S += sp[i * 1024 + h]; Q += sq[i * 1024 + h]; }
  float mean = S * (1.0f / 4096.0f);
  float var = Q * (1.0f / 4096.0f) - mean * mean;
  float av = g_[h] * rsqrtf(var + EPS);
  a[h] = av;
  c[h] = bt[h] - mean * av;
}

// ---------------- h1 = relu(bn(C1)) -> bf16 ----------------
__global__ void k_h1bf(const float* __restrict__ C1, const float* __restrict__ a,
                       const float* __restrict__ c, bf16* __restrict__ H1) {
  int i4 = blockIdx.x * 256 + threadIdx.x;  // over 1048576
  int col0 = (i4 * 4) & 1023;
  float4 v = ((const float4*)C1)[i4];
  float4 av = *(const float4*)(a + col0);
  float4 cv = *(const float4*)(c + col0);
  union { bf16 h[4]; uint2 u; } pk;
  pk.h[0] = (bf16)fmaxf(v.x * av.x + cv.x, 0.f);
  pk.h[1] = (bf16)fmaxf(v.y * av.y + cv.y, 0.f);
  pk.h[2] = (bf16)fmaxf(v.z * av.z + cv.z, 0.f);
  pk.h[3] = (bf16)fmaxf(v.w * av.w + cv.w, 0.f);
  *(uint2*)(H1 + (size_t)i4 * 4) = pk.u;
}

// ---------------- y[b] = sum_h relu(bn(C2)) * wout + bout ----------------
__global__ __launch_bounds__(256) void k_out(const float* __restrict__ C2,
                                             const float* __restrict__ a,
                                             const float* __restrict__ c,
                                             const float* __restrict__ wout,
                                             const float* __restrict__ bout,
                                             float* __restrict__ y) {
  int t = threadIdx.x;
  int w = t >> 6, lane = t & 63;
  int row = blockIdx.x * 4 + w;
  const float* cr = C2 + (size_t)row * 1024;
  float s = 0.f;
#pragma unroll
  for (int j = 0; j < 16; ++j) {
    int col = j * 64 + lane;
    float v = fmaxf(cr[col] * a[col] + c[col], 0.f);
    s += v * wout[col];
  }
#pragma unroll
  for (int off = 32; off > 0; off >>= 1) s += __shfl_xor(s, off, 64);
  if (lane == 0) y[row] = s + bout[0];
}

extern "C" void kernel_launch(void* const* d_in, const int* in_sizes, int n_in,
                              void* d_out, int out_size, void* d_ws, size_t ws_size,
                              hipStream_t stream) {
  (void)in_sizes; (void)n_in; (void)out_size; (void)ws_size;
  const int* x_id = (const int*)d_in[0];
  const float* x_value = (const float*)d_in[1];
  const float* emb = (const float*)d_in[2];
  const float* emb_g = (const float*)d_in[3];
  const float* embb = (const float*)d_in[4];
  const float* Qw = (const float*)d_in[5];
  const float* bil = (const float*)d_in[6];
  const float* vals = (const float*)d_in[7];
  const float* arm_g = (const float*)d_in[8];
  const float* w1 = (const float*)d_in[10];
  const float* g1 = (const float*)d_in[12];
  const float* bt1 = (const float*)d_in[13];
  const float* w2 = (const float*)d_in[14];
  const float* g2 = (const float*)d_in[16];
  const float* bt2 = (const float*)d_in[17];
  const float* wout = (const float*)d_in[18];
  const float* bout = (const float*)d_in[19];
  // b1, b2, arm_b unused: per-column shifts cancel exactly in train-mode BN.

  char* w = (char*)d_ws;
  float* ws_A = (float*)w;                  // 16 MB: xe -> C1 -> C2
  bf16* ws_arm = (bf16*)(w + 16777216);     // 32 MB
  bf16* ws_w1b = (bf16*)(w + 50331648);     // 8 MB: w1*scale; H1 after gemm1
  bf16* ws_H1 = ws_w1b;
  bf16* ws_w2b = (bf16*)(w + 58720256);     // 2 MB
  float* ws_kq = (float*)(w + 60817408);    // 16 KB
  float* misc = (float*)(w + 60833792);
  float* es_p = misc;             // 256*64
  float* eq_p = es_p + 16384;     // 256*64
  float* as_p = eq_p + 16384;     // 64*256
  float* aq_p = as_p + 16384;     // 64*256
  float* sp1 = aq_p + 16384;      // 32*1024
  float* sq1 = sp1 + 32768;
  float* sp2 = sq1 + 32768;
  float* sq2 = sp2 + 32768;
  float* eb_a = sq2 + 32768;      // 64
  float* eb_b = eb_a + 64;
  float* a1c = eb_b + 64;         // 1024
  float* c1c = a1c + 1024;
  float* a2c = c1c + 1024;
  float* c2c = a2c + 1024;

  k_embed<<<256, 256, 0, stream>>>(x_id, x_value, emb, ws_A, es_p, eq_p);
  k_prep<<<1, 256, 0, stream>>>(Qw, bil, ws_kq, es_p, eq_p, emb_g, embb, eb_a, eb_b);
  k_attn<<<4096, 256, 0, stream>>>(ws_A, ws_kq, eb_a, eb_b, vals, ws_arm);
  k_armstats<<<64, 256, 0, stream>>>(ws_arm, as_p, aq_p);
  k_cvtw<<<320, 256, 0, stream>>>(w1, w2, as_p, aq_p, arm_g, ws_w1b, ws_w2b);
  gemm_bt<<<dim3(32, 16), 256, 0, stream>>>(ws_arm, ws_w1b, ws_A, sp1, sq1, 4096);
  k_colfin<<<4, 256, 0, stream>>>(sp1, sq1, g1, bt1, a1c, c1c);
  k_h1bf<<<4096, 256, 0, stream>>>(ws_A, a1c, c1c, ws_H1);
  gemm_bt<<<dim3(32, 16), 256, 0, stream>>>(ws_H1, ws_w2b, ws_A, sp2, sq2, 1024);
  k_colfin<<<4, 256, 0, stream>>>(sp2, sq2, g2, bt2, a2c, c2c);
  k_out<<<1024, 256, 0, stream>>>(ws_A, a2c, c2c, wout, bout, (float*)d_out);
}